// Round 7
// baseline (602.473 us; speedup 1.0000x reference)
//
#include <hip/hip_runtime.h>

// LearnableSDFGrid: ray-box intersect + fixed-step march + 8-corner voxel gather.
// R=32768 rays, S=128 steps, 256^3 f32 grid, box [-1,1]^3, step 0.02.
// Outputs (concat flat): sdf [R,S,8], positions [R,S,8,3], valid [R,S] (as 0/1 f32).
//
// Round 7 (resubmit after broker timeout): occupancy probe. Round-4/5 used
// 32KB LDS -> 5 blocks/CU = 62% occupancy; scattered gathers (~200-500cy
// L2/L3 latency) may be latency-bound. Shrink LDS to 20KB (12KB pos staged in
// two record-halves + 8KB sdf) -> exactly 8 blocks/CU = 32 waves = 100%
// occupancy. __launch_bounds__(256,8) caps VGPR at 64 so registers don't cap
// occupancy instead.
// Retained: LDS store-transpose + full-line NT stores, z-pair f2 gathers,
// contract(off) numerics.

constexpr int   RAYS = 32768;
constexpr int   STEPS = 128;
constexpr float STEP = 0.02f;
constexpr float VOX = 2.0f / 255.0f;   // (max-min)/(n-1), rounded once in f32 like jnp

typedef float f4 __attribute__((ext_vector_type(4)));
typedef float f2 __attribute__((ext_vector_type(2), aligned(4)));  // 4B-aligned 8B load

__global__ __launch_bounds__(256, 8) void sdf_march_kernel(
    const float* __restrict__ org,
    const float* __restrict__ dir,
    const float* __restrict__ sdfv,
    float* __restrict__ out_sdf,    // R*S*8
    float* __restrict__ out_pos,    // R*S*8*3
    float* __restrict__ out_valid)  // R*S
{
#pragma clang fp contract(off)
    __shared__ f4 lds_pos[768];   // 12 KB: half the block's pos records at a time
    __shared__ f4 lds_sdf[512];   // 8 KB: block's sdf records

    const int tid = threadIdx.x;
    const int gid = blockIdx.x * 256 + tid;
    const int r = gid >> 7;       // ray
    const int s = gid & 127;      // step

    // --- ray-box intersection (faithful to reference, incl. t0 reuse in t1) ---
    const float ox = org[r * 3 + 0], oy = org[r * 3 + 1], oz = org[r * 3 + 2];
    const float dx = dir[r * 3 + 0], dy = dir[r * 3 + 1], dz = dir[r * 3 + 2];

    const float ivx = 1.0f / dx, ivy = 1.0f / dy, ivz = 1.0f / dz;
    const float axv = (-1.0f - ox) * ivx, ayv = (-1.0f - oy) * ivy, azv = (-1.0f - oz) * ivz;
    const float bxv = ( 1.0f - ox) * ivx, byv = ( 1.0f - oy) * ivy, bzv = ( 1.0f - oz) * ivz;
    const float t0 = fmaxf(fmaxf(fminf(axv, bxv), fminf(ayv, byv)), fminf(azv, bzv));
    const float t1 = fminf(fminf(fmaxf(t0, bxv), fmaxf(t0, byv)), fmaxf(t0, bzv));
    const bool hit = (t1 >= t0);

    // --- march: t = t0 + STEP*s (mul then add, separate rounding like numpy) ---
    const float ts = STEP * (float)s;
    const float t  = t0 + ts;
    const bool step_mask = (t < t1) && hit;

    // pts = o + t*d (mul then add; contract off)
    const float mx = t * dx, my = t * dy, mz = t * dz;
    const float px = ox + mx, py = oy + my, pz = oz + mz;

    // idx = trunc((p - minb)/vox) like .astype(int32)
    const float fx = (px + 1.0f) / VOX;
    const float fy = (py + 1.0f) / VOX;
    const float fz = (pz + 1.0f) / VOX;
    const int ix = (int)fx, iy = (int)fy, iz = (int)fz;
    const bool inb = (ix >= 0) & (ix < 255) & (iy >= 0) & (iy < 255) & (iz >= 0) & (iz < 255);
    const bool valid = inb && step_mask;

    const int ixc = min(max(ix, 0), 254);
    const int iyc = min(max(iy, 0), 254);
    const int izc = min(max(iz, 0), 254);

    f4 sv0 = {0.f, 0.f, 0.f, 0.f}, sv1 = {0.f, 0.f, 0.f, 0.f};
    float x0 = 0.f, x1 = 0.f, y0 = 0.f, y1 = 0.f, z0 = 0.f, z1 = 0.f;

    if (valid) {
        // 8-corner gather as 4 z-pair 8B loads.
        // corner order per OFFS: (0,0,0)(1,0,0)(0,1,0)(1,1,0)(0,0,1)(1,0,1)(0,1,1)(1,1,1)
        const int base = (ixc * 256 + iyc) * 256 + izc;
        const f2 vz00 = *(const f2*)(sdfv + base);                  // v000, v001
        const f2 vz10 = *(const f2*)(sdfv + base + 65536);          // v100, v101
        const f2 vz01 = *(const f2*)(sdfv + base + 256);            // v010, v011
        const f2 vz11 = *(const f2*)(sdfv + base + 65536 + 256);    // v110, v111
        sv0 = (f4){vz00.x, vz10.x, vz01.x, vz11.x};
        sv1 = (f4){vz00.y, vz10.y, vz01.y, vz11.y};

        // corner positions: minb + ci*vox (mul then add; contract off)
        x0 = -1.0f + (float)ixc * VOX;
        x1 = -1.0f + (float)(ixc + 1) * VOX;
        y0 = -1.0f + (float)iyc * VOX;
        y1 = -1.0f + (float)(iyc + 1) * VOX;
        z0 = -1.0f + (float)izc * VOX;
        z1 = -1.0f + (float)(izc + 1) * VOX;
    }

    // record layout [8,3] as 6 f4:
    // (x0,y0,z0)(x1,y0,z0)(x0,y1,z0)(x1,y1,z0)(x0,y0,z1)(x1,y0,z1)(x0,y1,z1)(x1,y1,z1)
    const int lrec = tid & 127;            // record slot within a half
    const bool lowHalf = (tid < 128);

    // stage sdf (all threads) + pos half A (threads 0..127)
    lds_sdf[tid * 2 + 0] = sv0;
    lds_sdf[tid * 2 + 1] = sv1;
    if (lowHalf) {
        f4* lp = lds_pos + lrec * 6;
        lp[0] = (f4){x0, y0, z0, x1};
        lp[1] = (f4){y0, z0, x0, y1};
        lp[2] = (f4){z0, x1, y1, z0};
        lp[3] = (f4){x0, y0, z1, x1};
        lp[4] = (f4){y0, z1, x0, y1};
        lp[5] = (f4){z1, x1, y1, z1};
    }

    // valid: 1 dword/lane, coalesced full-line stream
    __builtin_nontemporal_store(valid ? 1.0f : 0.0f, out_valid + gid);

    __syncthreads();

    // readout: sdf (512 f4) + pos half A (768 f4), lane-contiguous NT streams
    f4* os = (f4*)out_sdf + (size_t)blockIdx.x * 512;
    __builtin_nontemporal_store(lds_sdf[tid],       os + tid);
    __builtin_nontemporal_store(lds_sdf[tid + 256], os + tid + 256);

    f4* op = (f4*)out_pos + (size_t)blockIdx.x * 1536;
#pragma unroll
    for (int k = 0; k < 3; ++k) {
        __builtin_nontemporal_store(lds_pos[tid + 256 * k], op + tid + 256 * k);
    }

    __syncthreads();

    // stage pos half B (threads 128..255)
    if (!lowHalf) {
        f4* lp = lds_pos + lrec * 6;
        lp[0] = (f4){x0, y0, z0, x1};
        lp[1] = (f4){y0, z0, x0, y1};
        lp[2] = (f4){z0, x1, y1, z0};
        lp[3] = (f4){x0, y0, z1, x1};
        lp[4] = (f4){y0, z1, x0, y1};
        lp[5] = (f4){z1, x1, y1, z1};
    }

    __syncthreads();

#pragma unroll
    for (int k = 0; k < 3; ++k) {
        __builtin_nontemporal_store(lds_pos[tid + 256 * k], op + 768 + tid + 256 * k);
    }
}

extern "C" void kernel_launch(void* const* d_in, const int* in_sizes, int n_in,
                              void* d_out, int out_size, void* d_ws, size_t ws_size,
                              hipStream_t stream) {
    const float* origins    = (const float*)d_in[0];
    const float* directions = (const float*)d_in[1];
    const float* sdf_values = (const float*)d_in[2];

    float* out = (float*)d_out;
    float* out_sdf   = out;                                   // 32768*128*8   = 33554432
    float* out_pos   = out + 33554432;                        // 32768*128*8*3 = 100663296
    float* out_valid = out + 33554432 + 100663296;            // 32768*128     = 4194304

    const int total = RAYS * STEPS;                           // 4194304
    dim3 grid(total / 256), block(256);
    sdf_march_kernel<<<grid, block, 0, stream>>>(origins, directions, sdf_values,
                                                 out_sdf, out_pos, out_valid);
}

// Round 8
// 591.815 us; speedup vs baseline: 1.0180x; 1.0180x over previous
//
#include <hip/hip_runtime.h>

// LearnableSDFGrid: ray-box intersect + fixed-step march + 8-corner voxel gather.
// R=32768 rays, S=128 steps, 256^3 f32 grid, box [-1,1]^3, step 0.02.
// Outputs (concat flat): sdf [R,S,8], positions [R,S,8,3], valid [R,S] (as 0/1 f32).
//
// Round 8: gather-early / consume-late. In round 4/5 the gather->LDS chain sat
// before the single barrier, so L2/L3 gather latency (~200-500cy) delayed the
// barrier and the pos store stream (75% of write traffic, independent of the
// gathers) couldn't start. Now: issue gathers first, stage+store pos while
// they're in flight, consume gather results after the pos readout, then stage+
// store sdf behind a second barrier. Same 32KB LDS, same bit-exact numerics.
// Retained: LDS store-transpose + full-line NT stores, z-pair f2 gathers,
// contract(off) numerics.

constexpr int   RAYS = 32768;
constexpr int   STEPS = 128;
constexpr float STEP = 0.02f;
constexpr float VOX = 2.0f / 255.0f;   // (max-min)/(n-1), rounded once in f32 like jnp

typedef float f4 __attribute__((ext_vector_type(4)));
typedef float f2 __attribute__((ext_vector_type(2), aligned(4)));  // 4B-aligned 8B load

__global__ __launch_bounds__(256) void sdf_march_kernel(
    const float* __restrict__ org,
    const float* __restrict__ dir,
    const float* __restrict__ sdfv,
    float* __restrict__ out_sdf,    // R*S*8
    float* __restrict__ out_pos,    // R*S*8*3
    float* __restrict__ out_valid)  // R*S
{
#pragma clang fp contract(off)
    __shared__ f4 lds_pos[1536];  // 24 KB: block's pos records
    __shared__ f4 lds_sdf[512];   // 8 KB: block's sdf records

    const int tid = threadIdx.x;
    const int gid = blockIdx.x * 256 + tid;
    const int r = gid >> 7;       // ray
    const int s = gid & 127;      // step

    // --- ray-box intersection (faithful to reference, incl. t0 reuse in t1) ---
    const float ox = org[r * 3 + 0], oy = org[r * 3 + 1], oz = org[r * 3 + 2];
    const float dx = dir[r * 3 + 0], dy = dir[r * 3 + 1], dz = dir[r * 3 + 2];

    const float ivx = 1.0f / dx, ivy = 1.0f / dy, ivz = 1.0f / dz;
    const float axv = (-1.0f - ox) * ivx, ayv = (-1.0f - oy) * ivy, azv = (-1.0f - oz) * ivz;
    const float bxv = ( 1.0f - ox) * ivx, byv = ( 1.0f - oy) * ivy, bzv = ( 1.0f - oz) * ivz;
    const float t0 = fmaxf(fmaxf(fminf(axv, bxv), fminf(ayv, byv)), fminf(azv, bzv));
    const float t1 = fminf(fminf(fmaxf(t0, bxv), fmaxf(t0, byv)), fmaxf(t0, bzv));
    const bool hit = (t1 >= t0);

    // --- march: t = t0 + STEP*s (mul then add, separate rounding like numpy) ---
    const float ts = STEP * (float)s;
    const float t  = t0 + ts;
    const bool step_mask = (t < t1) && hit;

    // pts = o + t*d (mul then add; contract off)
    const float mx = t * dx, my = t * dy, mz = t * dz;
    const float px = ox + mx, py = oy + my, pz = oz + mz;

    // idx = trunc((p - minb)/vox) like .astype(int32)
    const float fx = (px + 1.0f) / VOX;
    const float fy = (py + 1.0f) / VOX;
    const float fz = (pz + 1.0f) / VOX;
    const int ix = (int)fx, iy = (int)fy, iz = (int)fz;
    const bool inb = (ix >= 0) & (ix < 255) & (iy >= 0) & (iy < 255) & (iz >= 0) & (iz < 255);
    const bool valid = inb && step_mask;

    const int ixc = min(max(ix, 0), 254);
    const int iyc = min(max(iy, 0), 254);
    const int izc = min(max(iz, 0), 254);

    // --- issue gathers EARLY; results consumed after the pos readout ---
    // corner order per OFFS: (0,0,0)(1,0,0)(0,1,0)(1,1,0)(0,0,1)(1,0,1)(0,1,1)(1,1,1)
    f2 vz00 = {0.f, 0.f}, vz10 = {0.f, 0.f}, vz01 = {0.f, 0.f}, vz11 = {0.f, 0.f};
    if (valid) {
        const int base = (ixc * 256 + iyc) * 256 + izc;
        vz00 = *(const f2*)(sdfv + base);                  // v000, v001
        vz10 = *(const f2*)(sdfv + base + 65536);          // v100, v101
        vz01 = *(const f2*)(sdfv + base + 256);            // v010, v011
        vz11 = *(const f2*)(sdfv + base + 65536 + 256);    // v110, v111
    }

    // --- pos scalars (VALU only, no dependence on gathers) ---
    float x0 = 0.f, x1 = 0.f, y0 = 0.f, y1 = 0.f, z0 = 0.f, z1 = 0.f;
    if (valid) {
        x0 = -1.0f + (float)ixc * VOX;
        x1 = -1.0f + (float)(ixc + 1) * VOX;
        y0 = -1.0f + (float)iyc * VOX;
        y1 = -1.0f + (float)(iyc + 1) * VOX;
        z0 = -1.0f + (float)izc * VOX;
        z1 = -1.0f + (float)(izc + 1) * VOX;
    }

    // stage pos records [8,3] as 6 f4:
    // (x0,y0,z0)(x1,y0,z0)(x0,y1,z0)(x1,y1,z0)(x0,y0,z1)(x1,y0,z1)(x0,y1,z1)(x1,y1,z1)
    f4* lp = lds_pos + tid * 6;
    lp[0] = (f4){x0, y0, z0, x1};
    lp[1] = (f4){y0, z0, x0, y1};
    lp[2] = (f4){z0, x1, y1, z0};
    lp[3] = (f4){x0, y0, z1, x1};
    lp[4] = (f4){y0, z1, x0, y1};
    lp[5] = (f4){z1, x1, y1, z1};

    // valid: 1 dword/lane, coalesced full-line stream
    __builtin_nontemporal_store(valid ? 1.0f : 0.0f, out_valid + gid);

    __syncthreads();

    // pos readout: 1536 f4 lane-contiguous NT stream (gathers still in flight)
    f4* op = (f4*)out_pos + (size_t)blockIdx.x * 1536;
#pragma unroll
    for (int k = 0; k < 6; ++k) {
        __builtin_nontemporal_store(lds_pos[tid + 256 * k], op + tid + 256 * k);
    }

    // --- consume gathers now (vmcnt wait lands here, after the store stream) ---
    const f4 sv0 = (f4){vz00.x, vz10.x, vz01.x, vz11.x};
    const f4 sv1 = (f4){vz00.y, vz10.y, vz01.y, vz11.y};
    lds_sdf[tid * 2 + 0] = sv0;
    lds_sdf[tid * 2 + 1] = sv1;

    __syncthreads();

    // sdf readout: 512 f4 lane-contiguous NT stream
    f4* os = (f4*)out_sdf + (size_t)blockIdx.x * 512;
    __builtin_nontemporal_store(lds_sdf[tid],       os + tid);
    __builtin_nontemporal_store(lds_sdf[tid + 256], os + tid + 256);
}

extern "C" void kernel_launch(void* const* d_in, const int* in_sizes, int n_in,
                              void* d_out, int out_size, void* d_ws, size_t ws_size,
                              hipStream_t stream) {
    const float* origins    = (const float*)d_in[0];
    const float* directions = (const float*)d_in[1];
    const float* sdf_values = (const float*)d_in[2];

    float* out = (float*)d_out;
    float* out_sdf   = out;                                   // 32768*128*8   = 33554432
    float* out_pos   = out + 33554432;                        // 32768*128*8*3 = 100663296
    float* out_valid = out + 33554432 + 100663296;            // 32768*128     = 4194304

    const int total = RAYS * STEPS;                           // 4194304
    dim3 grid(total / 256), block(256);
    sdf_march_kernel<<<grid, block, 0, stream>>>(origins, directions, sdf_values,
                                                 out_sdf, out_pos, out_valid);
}